// Round 6
// baseline (301.046 us; speedup 1.0000x reference)
//
#include <hip/hip_runtime.h>
#include <hip/hip_bf16.h>

// 3D conv K=2 VALID + (y+1)^2 via mfma_f32_32x32x16_bf16 — occupancy build.
// x: (8,16,64,64,64) f32; w: (32,128) f32, k = c*8 + kd*4 + kh*2 + kw.
// out: (8,32,63,63,63) f32.
//
// R4 compute/store structure kept (K permuted to k' = tap*16+c, LDS slab
// [h][w64][c16] bf16, one ds_read_b128 per B fragment, 32-lane w-run
// stores). R6 changes, targeting the latency-bound/low-TLP diagnosis:
//  - h-tile 8 -> 4: LDS = 2 slabs x [5h][64w][16c] = 20,544 B -> 7 blocks
//    = 28 waves/CU (was 37.4 KB -> ~12.5 waves). __launch_bounds__(256,7).
//  - rolling-d/prefetch dropped (null in R3 and R5): per-d blocks, grid
//    16,128, one barrier per block.
//  - XCD-chunked block swizzle: tid = (bid%8)*1008 + bid/8 gives each XCD
//    one full batch b (63 d x 16 h contiguous) -> slab overlap between
//    d-neighbors is XCD-local L2 reuse.

typedef __attribute__((ext_vector_type(8)))  short short8;
typedef __attribute__((ext_vector_type(4)))  float f32x4;
typedef __attribute__((ext_vector_type(16))) float f32x16;
typedef __attribute__((ext_vector_type(4)))  unsigned short u16x4;

#define XCS 262144        // 64^3 x channel stride (f32)
#define OS  250047        // 63^3 out channel stride (f32)
#define SLAB_E 5120       // 5*64*16 u16 per d-slab

__device__ __forceinline__ unsigned short f2bf(float f) {
    unsigned int u = __builtin_bit_cast(unsigned int, f);
    return (unsigned short)((u + 0x7fffu + ((u >> 16) & 1u)) >> 16);
}

__global__ __launch_bounds__(256, 7) void conv3d_k2_occ(
    const float* __restrict__ x,
    const float* __restrict__ wgt,
    float* __restrict__ out)
{
    __shared__ unsigned short tile[2 * SLAB_E + 32];   // 20,544 B

    const int t   = threadIdx.x;
    const int l   = t & 63;
    const int wv  = t >> 6;        // wave 0..3 -> h row
    const int col = l & 31;        // MFMA col (w) / A row (o)
    const int kh8 = l >> 5;        // k-half -> c-half

    // XCD-chunked swizzle: 8064 blocks, XCD k owns tid in [k*1008,(k+1)*1008)
    // = exactly batch b = k, d innermost -> d-neighbor slab reuse in-XCD.
    const int bid = blockIdx.x;
    const int tid = (bid & 7) * 1008 + (bid >> 3);
    const int b   = tid / 1008;
    const int rr  = tid - b * 1008;
    const int ht  = rr / 63;
    const int d   = rr - ht * 63;  // 0..62
    const int h0  = ht * 4;        // 4 output h rows (h0..h0+3)

    // ---- A fragments: 64 contiguous floats per lane, compile-time shuffle ----
    short8 aF[8];
    {
        f32x4 wreg[16];
        const float* wp = wgt + col * 128 + kh8 * 64;
#pragma unroll
        for (int q = 0; q < 16; ++q) wreg[q] = *(const f32x4*)(wp + q * 4);
#pragma unroll
        for (int tap = 0; tap < 8; ++tap) {
            short8 a;
#pragma unroll
            for (int j = 0; j < 8; ++j) {
                const int k = j * 8 + tap;
                a[j] = (short)f2bf(wreg[k >> 2][k & 3]);
            }
            aF[tap] = a;
        }
    }

    // ---- stage slabs d, d+1 into [h5][w64][c16] bf16 ----
    {
        const int sw = t & 63;     // w: 64 lanes -> 256-B segment per load
        const int cq = t >> 6;     // c-quad
#pragma unroll
        for (int p = 0; p < 2; ++p) {
            const float* xs = x + (size_t)b * 16 * XCS + (size_t)(d + p) * 4096;
            float v[5][4];
#pragma unroll
            for (int h = 0; h < 5; ++h) {
                int hp = h0 + h; if (hp > 63) hp = 63;
#pragma unroll
                for (int i = 0; i < 4; ++i)
                    v[h][i] = xs[(size_t)(cq * 4 + i) * XCS + hp * 64 + sw];
            }
#pragma unroll
            for (int h = 0; h < 5; ++h) {
                u16x4 pk;
#pragma unroll
                for (int i = 0; i < 4; ++i) pk[i] = f2bf(v[h][i]);
                *(u16x4*)&tile[p * SLAB_E + h * 1024 + sw * 16 + cq * 4] = pk;
            }
        }
    }
    __syncthreads();

    // ---- compute: wave owns h row wv, w-halves {0,32} ----
    const int hl = wv;
#pragma unroll
    for (int wh = 0; wh < 2; ++wh) {
        const int wb = wh * 32;
        f32x16 acc = {};
#pragma unroll
        for (int kd = 0; kd < 2; ++kd)
#pragma unroll
        for (int kh = 0; kh < 2; ++kh)
#pragma unroll
        for (int kw = 0; kw < 2; ++kw) {
            const int tap = kd * 4 + kh * 2 + kw;
            short8 bfrag = *(const short8*)&tile[kd * SLAB_E
                + (hl + kh) * 1024 + (wb + col + kw) * 16 + kh8 * 8];
            acc = __builtin_amdgcn_mfma_f32_32x32x16_bf16(aF[tap], bfrag, acc, 0, 0, 0);
        }
        const int h  = h0 + hl;
        const int wc = wb + col;
        if (h < 63 && wc < 63) {
            float* ob = out + (size_t)b * 32 * OS + (size_t)d * 3969
                            + h * 63 + wc;
#pragma unroll
            for (int r = 0; r < 16; ++r) {
                const int o = (r & 3) + 8 * (r >> 2) + 4 * kh8;  // D row map
                float y = acc[r] + 1.0f;
                ob[(size_t)o * OS] = y * y;
            }
        }
    }
}

extern "C" void kernel_launch(void* const* d_in, const int* in_sizes, int n_in,
                              void* d_out, int out_size, void* d_ws, size_t ws_size,
                              hipStream_t stream) {
    const float* x   = (const float*)d_in[0];
    const float* wgt = (const float*)d_in[1];
    float* out = (float*)d_out;

    dim3 grid(8064);   // 16 h-tiles x 63 d x 8 b, XCD-chunk swizzled in-kernel
    dim3 block(256);
    conv3d_k2_occ<<<grid, block, 0, stream>>>(x, wgt, out);
}

// Round 7
// 137.486 us; speedup vs baseline: 2.1896x; 2.1896x over previous
//
#include <hip/hip_runtime.h>
#include <hip/hip_bf16.h>

// 3D conv K=2 VALID + (y+1)^2 via mfma_f32_32x32x16_bf16 + LDS-staged stores.
// x: (8,16,64,64,64) f32; w: (32,128) f32, k = c*8 + kd*4 + kh*2 + kw.
// out: (8,32,63,63,63) f32.
//
// R4 geometry kept (best: 140 us, FETCH 96 MB): block = (b, d, 8 h-rows),
// grid (8,63,8) linear -> d-neighbors land 8 bids apart = same XCD ->
// kd slab overlap is L2-local. K permuted to k' = tap*16+c, input slab
// [h9][w64][c16] bf16, one ds_read_b128 per B fragment.
//
// NEW (R7): store-pattern fix. R4's epilogue stores wrote 2x128-B unaligned
// segments 4 MB apart per instruction (dur tracked hbm_bytes at ~2.9 TB/s).
// Now: all 4 acc tiles stay in regs; 2-pass epilogue scatters (y+1)^2 into
// an LDS image [16 o][504 (=8h*63w)] f32 (reuses input-tile LDS, 32.3 KB),
// then drains each o's 2016-B CONTIGUOUS run with 64-lane consecutive-dword
// stores = one 256-B segment per instr, sequential per run.

typedef __attribute__((ext_vector_type(8)))  short short8;
typedef __attribute__((ext_vector_type(4)))  float f32x4;
typedef __attribute__((ext_vector_type(16))) float f32x16;
typedef __attribute__((ext_vector_type(4)))  unsigned short u16x4;

#define XCS 262144        // 64^3 x channel stride (f32)
#define OS  250047        // 63^3 out channel stride (f32)
#define SLAB_E 9216       // 9*64*16 u16 per d-slab

__device__ __forceinline__ unsigned short f2bf(float f) {
    unsigned int u = __builtin_bit_cast(unsigned int, f);
    return (unsigned short)((u + 0x7fffu + ((u >> 16) & 1u)) >> 16);
}

__global__ __launch_bounds__(256, 4) void conv3d_k2_st(
    const float* __restrict__ x,
    const float* __restrict__ wgt,
    float* __restrict__ out)
{
    __shared__ __align__(16) unsigned char lds_raw[36928];
    unsigned short* tile = (unsigned short*)lds_raw;   // input [2][9][64][16] bf16
    float* ot = (float*)lds_raw;                        // epilogue [16][504] f32

    const int t   = threadIdx.x;
    const int l   = t & 63;
    const int wv  = t >> 6;        // wave 0..3
    const int col = l & 31;        // MFMA col (w) / A row (o)
    const int kh8 = l >> 5;        // k-half -> c-half

    const int h0 = blockIdx.x * 8; // 8 output h rows
    const int d  = blockIdx.y;     // 0..62
    const int b  = blockIdx.z;

    // ---- A fragments: 64 contiguous floats per lane, compile-time shuffle ----
    short8 aF[8];
    {
        f32x4 wreg[16];
        const float* wp = wgt + col * 128 + kh8 * 64;
#pragma unroll
        for (int q = 0; q < 16; ++q) wreg[q] = *(const f32x4*)(wp + q * 4);
#pragma unroll
        for (int tap = 0; tap < 8; ++tap) {
            short8 a;
#pragma unroll
            for (int j = 0; j < 8; ++j) {
                const int k = j * 8 + tap;
                a[j] = (short)f2bf(wreg[k >> 2][k & 3]);
            }
            aF[tap] = a;
        }
    }

    // ---- stage slabs d, d+1 into [h9][w64][c16] bf16 (R4 exact) ----
    {
        const int sw = t & 63;
        const int cq = t >> 6;
#pragma unroll
        for (int p = 0; p < 2; ++p) {
            const float* xs = x + (size_t)b * 16 * XCS + (size_t)(d + p) * 4096;
            float v[9][4];
#pragma unroll
            for (int h = 0; h < 9; ++h) {
                int hp = h0 + h; if (hp > 63) hp = 63;
#pragma unroll
                for (int i = 0; i < 4; ++i)
                    v[h][i] = xs[(size_t)(cq * 4 + i) * XCS + hp * 64 + sw];
            }
#pragma unroll
            for (int h = 0; h < 9; ++h) {
                u16x4 pk;
#pragma unroll
                for (int i = 0; i < 4; ++i) pk[i] = f2bf(v[h][i]);
                *(u16x4*)&tile[p * SLAB_E + h * 1024 + sw * 16 + cq * 4] = pk;
            }
        }
    }
    __syncthreads();

    // ---- compute: all 4 acc tiles (2 h-rows x 2 w-halves), kept in regs ----
    f32x16 acc[2][2];
#pragma unroll
    for (int th = 0; th < 2; ++th) {
        const int hl = wv * 2 + th;
#pragma unroll
        for (int wh = 0; wh < 2; ++wh) {
            const int wb = wh * 32;
            f32x16 a = {};
#pragma unroll
            for (int kd = 0; kd < 2; ++kd)
#pragma unroll
            for (int kh = 0; kh < 2; ++kh)
#pragma unroll
            for (int kw = 0; kw < 2; ++kw) {
                const int tap = kd * 4 + kh * 2 + kw;
                short8 bfrag = *(const short8*)&tile[kd * SLAB_E
                    + (hl + kh) * 1024 + (wb + col + kw) * 16 + kh8 * 8];
                a = __builtin_amdgcn_mfma_f32_32x32x16_bf16(aF[tap], bfrag, a, 0, 0, 0);
            }
            acc[th][wh] = a;
        }
    }
    __syncthreads();   // done reading input LDS; safe to overwrite

    // ---- epilogue: 2 passes of 16 o-planes each, LDS-staged stores ----
    const int runlen = (h0 == 56) ? 441 : 504;   // valid dwords per o-run
#pragma unroll
    for (int p = 0; p < 2; ++p) {
        // scatter (y+1)^2 into LDS image [16 o][504]
#pragma unroll
        for (int th = 0; th < 2; ++th) {
            const int hl = wv * 2 + th;
#pragma unroll
            for (int wh = 0; wh < 2; ++wh) {
                const int wc = wh * 32 + col;
                if (wc < 63) {
#pragma unroll
                    for (int r = 0; r < 8; ++r) {
                        const int rr = p * 8 + r;
                        const int ol = (rr & 3) + 8 * (rr >> 2) + 4 * kh8 - p * 16;
                        float y = acc[th][wh][rr] + 1.0f;
                        ot[ol * 504 + hl * 63 + wc] = y * y;
                    }
                }
            }
        }
        __syncthreads();
        // drain: wave wv owns 4 o-runs; each run = 2016 B contiguous in global
        float* dstb = out + ((size_t)b * 32 + p * 16) * OS + (size_t)d * 3969 + h0 * 63;
#pragma unroll
        for (int orun = 0; orun < 4; ++orun) {
            const int ol = wv * 4 + orun;
            const float* src = ot + ol * 504;
            float* dst = dstb + (size_t)ol * OS;
#pragma unroll
            for (int i = 0; i < 8; ++i) {
                const int idx = i * 64 + l;
                if (idx < runlen) dst[idx] = src[idx];
            }
        }
        __syncthreads();
    }
}

extern "C" void kernel_launch(void* const* d_in, const int* in_sizes, int n_in,
                              void* d_out, int out_size, void* d_ws, size_t ws_size,
                              hipStream_t stream) {
    const float* x   = (const float*)d_in[0];
    const float* wgt = (const float*)d_in[1];
    float* out = (float*)d_out;

    dim3 grid(8, 63, 8);    // h-tiles, d, b (linear order = R4's L2-friendly map)
    dim3 block(256);
    conv3d_k2_st<<<grid, block, 0, stream>>>(x, wgt, out);
}

// Round 8
// 109.316 us; speedup vs baseline: 2.7539x; 1.2577x over previous
//
#include <hip/hip_runtime.h>
#include <hip/hip_bf16.h>

// 3D conv K=2 VALID + (y+1)^2, mfma_f32_32x32x16_bf16, FULLY VECTORIZED
// global streams (16 B/lane both directions).
// x: (8,16,64,64,64) f32; w: (32,128) f32, k = c*8 + kd*4 + kh*2 + kw.
// out: (8,32,63,63,63) f32.
//
// Theory: dword (4 B/lane) global streams cap ~2.8 TB/s on MI355X (R4/R6/R7
// all pinned there); dwordx4 reaches ~7 TB/s (fillBuffer, m13). So:
//  LOADS:  dwordx4 w-runs (18/thread vs 72 scalar) -> wave-private 2-stage
//          LDS transpose: bf16 strip [c][3h][w64] (same wave writes+reads its
//          own 4 c-rows -> no barrier), then u16x4 -> tile [h][w][c16].
//  TILE:   c-halves XOR-swizzled by w&1: halves staging-write conflicts,
//          fragment ds_read_b128 stays 16-B aligned and bank-balanced.
//  STORES: LDS image [16 runs][520 dw], each run stored SHIFTED by base&3 so
//          aligned global positions are aligned in LDS; drain = <=3 head
//          dwords + 2x global_store_dwordx4 rounds + <=3 tail per 504-dw run.
// Compute identical to R4/R7 (K permuted to k' = tap*16+c, one b128/fragment,
// 32 MFMA/wave). Grid (8,63,8) linear (R4's L2-friendly map). 43 KB LDS ->
// 3 blocks/CU.

typedef __attribute__((ext_vector_type(8)))  short short8;
typedef __attribute__((ext_vector_type(4)))  float f32x4;
typedef __attribute__((ext_vector_type(16))) float f32x16;
typedef __attribute__((ext_vector_type(4)))  unsigned short u16x4;

#define XCS 262144        // 64^3 x channel stride (f32)
#define OS  250047        // 63^3 out channel stride (f32)
#define SLAB_E 9216       // 9*64*16 u16 per d-slab
#define IMG_DW 520        // dwords per epilogue run slot (504 + shift pad)

__device__ __forceinline__ unsigned short f2bf(float f) {
    unsigned int u = __builtin_bit_cast(unsigned int, f);
    return (unsigned short)((u + 0x7fffu + ((u >> 16) & 1u)) >> 16);
}

__global__ __launch_bounds__(256, 3) void conv3d_k2_vec(
    const float* __restrict__ x,
    const float* __restrict__ wgt,
    float* __restrict__ out)
{
    __shared__ __align__(16) unsigned char lds_raw[43008];
    unsigned short* tile  = (unsigned short*)lds_raw;            // [2][9][64][16] u16
    unsigned short* strip = (unsigned short*)(lds_raw + 36864);  // [16c][3h][64w] u16
    float* img = (float*)lds_raw;                                 // [16][520] f32

    const int t   = threadIdx.x;
    const int l   = t & 63;
    const int wv  = t >> 6;        // wave 0..3
    const int col = l & 31;        // MFMA col (w) / A row (o)
    const int kh8 = l >> 5;        // k-half -> c-half

    const int h0 = blockIdx.x * 8; // 8 output h rows
    const int d  = blockIdx.y;     // 0..62
    const int b  = blockIdx.z;

    // ---- A fragments: 64 contiguous floats per lane, compile-time shuffle ----
    short8 aF[8];
    {
        f32x4 wreg[16];
        const float* wp = wgt + col * 128 + kh8 * 64;
#pragma unroll
        for (int q = 0; q < 16; ++q) wreg[q] = *(const f32x4*)(wp + q * 4);
#pragma unroll
        for (int tap = 0; tap < 8; ++tap) {
            short8 a;
#pragma unroll
            for (int j = 0; j < 8; ++j) {
                const int k = j * 8 + tap;
                a[j] = (short)f2bf(wreg[k >> 2][k & 3]);
            }
            aF[tap] = a;
        }
    }

    // ---- staging: dwordx4 loads + wave-private 2-stage LDS transpose ----
    // stage A: thread (cA = t>>4, wq = t&15) loads 16-B w-runs of c-plane cA.
    // stage B: thread (wB = l, cq = wv) gathers c-quad cq*4..+3 at w = wB.
    // wave wv's strip region = c rows wv*4..+3: written AND read by wave wv
    // only -> no barrier inside staging.
    const int cA = t >> 4;
    const int wq = t & 15;
    const int wB = l;
    const int cq = wv;

#pragma unroll
    for (int p = 0; p < 2; ++p) {
        const float* xs = x + (size_t)b * 16 * XCS + (size_t)(d + p) * 4096;
        f32x4 v[9];
#pragma unroll
        for (int h = 0; h < 9; ++h) {
            int hp = h0 + h; if (hp > 63) hp = 63;
            v[h] = *(const f32x4*)(xs + (size_t)cA * XCS + hp * 64 + wq * 4);
        }
#pragma unroll
        for (int hr = 0; hr < 3; ++hr) {
#pragma unroll
            for (int j = 0; j < 3; ++j) {
                u16x4 pk;
#pragma unroll
                for (int i = 0; i < 4; ++i) pk[i] = f2bf(v[hr * 3 + j][i]);
                *(u16x4*)&strip[cA * 192 + j * 64 + wq * 4] = pk;
            }
#pragma unroll
            for (int j = 0; j < 3; ++j) {
                const int h = hr * 3 + j;
                u16x4 q;
#pragma unroll
                for (int i = 0; i < 4; ++i)
                    q[i] = strip[(cq * 4 + i) * 192 + j * 64 + wB];
                const int cb = (cq * 4) ^ ((wB & 1) << 3);   // XOR swizzle
                *(u16x4*)&tile[p * SLAB_E + h * 1024 + wB * 16 + cb] = q;
            }
        }
    }
    __syncthreads();

    // ---- compute: 4 acc tiles (2 h-rows x 2 w-halves) kept in regs ----
    f32x16 acc[2][2];
#pragma unroll
    for (int th = 0; th < 2; ++th) {
        const int hl = wv * 2 + th;
#pragma unroll
        for (int wh = 0; wh < 2; ++wh) {
            const int wb = wh * 32;
            f32x16 a = {};
#pragma unroll
            for (int kd = 0; kd < 2; ++kd)
#pragma unroll
            for (int kh = 0; kh < 2; ++kh)
#pragma unroll
            for (int kw = 0; kw < 2; ++kw) {
                const int tap = kd * 4 + kh * 2 + kw;
                const int xw  = wb + col + kw;
                short8 bfrag = *(const short8*)&tile[kd * SLAB_E
                    + (hl + kh) * 1024 + xw * 16 + ((kh8 * 8) ^ ((xw & 1) << 3))];
                a = __builtin_amdgcn_mfma_f32_32x32x16_bf16(aF[tap], bfrag, a, 0, 0, 0);
            }
            acc[th][wh] = a;
        }
    }
    __syncthreads();   // done reading tile; LDS becomes the store image

    // ---- epilogue: 2 passes x 16 o-runs, shift-aligned dwordx4 drain ----
    const int hvalid = (h0 == 56) ? 7 : 8;
    const int runlen = hvalid * 63;
#pragma unroll
    for (int p = 0; p < 2; ++p) {
        // scatter (y+1)^2 into img, shifted by each run's base&3
#pragma unroll
        for (int th = 0; th < 2; ++th) {
            const int hl = wv * 2 + th;
            if (hl < hvalid) {
#pragma unroll
                for (int wh = 0; wh < 2; ++wh) {
                    const int wc = wh * 32 + col;
                    if (wc < 63) {
#pragma unroll
                        for (int r = 0; r < 8; ++r) {
                            const int rr = p * 8 + r;
                            const int og = (rr & 3) + 8 * (rr >> 2) + 4 * kh8;
                            const int ol = og - p * 16;
                            const unsigned sh =
                                (3u * (unsigned)(32 * b + og) + (unsigned)d + 3u * (unsigned)h0) & 3u;
                            float y = acc[th][wh][rr] + 1.0f;
                            img[ol * IMG_DW + (int)sh + hl * 63 + wc] = y * y;
                        }
                    }
                }
            }
        }
        __syncthreads();
        // drain: wave wv owns 4 runs; head(<=3) + 2x dwordx4 + tail(<=3)
#pragma unroll
        for (int orun = 0; orun < 4; ++orun) {
            const int ol = wv * 4 + orun;
            const int og = p * 16 + ol;
            const size_t base_dw = ((size_t)b * 32 + og) * (size_t)OS
                                 + (size_t)d * 3969 + (size_t)h0 * 63;
            float* gp = out + base_dw;
            const int sh = (int)(base_dw & 3);
            const int g0 = (4 - sh) & 3;
            const float* ip = img + ol * IMG_DW + sh;
            if (l < g0) gp[l] = ip[l];
            const int nv = (runlen - g0) >> 2;
#pragma unroll
            for (int rnd = 0; rnd < 2; ++rnd) {
                const int k = rnd * 64 + l;
                if (k < nv) {
                    f32x4 qv = *(const f32x4*)(ip + g0 + 4 * k);
                    *(f32x4*)(gp + g0 + 4 * k) = qv;
                }
            }
            const int kt = g0 + 4 * nv + l;
            if (kt < runlen) gp[kt] = ip[kt];
        }
        if (p == 0) __syncthreads();   // img reused by pass 1 scatter
    }
}

extern "C" void kernel_launch(void* const* d_in, const int* in_sizes, int n_in,
                              void* d_out, int out_size, void* d_ws, size_t ws_size,
                              hipStream_t stream) {
    const float* x   = (const float*)d_in[0];
    const float* wgt = (const float*)d_in[1];
    float* out = (float*)d_out;

    dim3 grid(8, 63, 8);    // h-tiles, d, b (linear = L2-friendly map from R4)
    dim3 block(256);
    conv3d_k2_vec<<<grid, block, 0, stream>>>(x, wgt, out);
}

// Round 9
// 83.374 us; speedup vs baseline: 3.6108x; 1.3111x over previous
//
#include <hip/hip_runtime.h>
#include <hip/hip_bf16.h>

// 3D conv K=2 VALID + (y+1)^2, mfma_f32_32x32x16_bf16, vectorized streams.
// x: (8,16,64,64,64) f32; w: (32,128) f32, k = c*8 + kd*4 + kh*2 + kw.
// out: (8,32,63,63,63) f32.
//
// R8 + three changes:
//  1) strip double-buffered per-h [2][16c][64w] (4 KB): LDS = 40960 B ->
//     exactly 4 blocks/CU (16 waves), launch_bounds(256,4). More cross-block
//     phase overlap (load-burst / MFMA / store-burst).
//  2) non-temporal output stores: write-once data bypasses L2 -> keeps L2
//     for the x-slab halo reuse (FETCH 96 MB < 128 logical).
//  3) tile relayout [kd][kh8][9h][64w][8c] (w-stride 16 B): compute
//     ds_read_b128 conflict-free (was ~2x), staging ds_write 2-way = free
//     (was ~16-way, the 5M conflict cycles in R4-R7). No XOR swizzle needed.
// Compute/epilogue structure otherwise identical to R8.

typedef __attribute__((ext_vector_type(8)))  short short8;
typedef __attribute__((ext_vector_type(4)))  float f32x4;
typedef __attribute__((ext_vector_type(16))) float f32x16;
typedef __attribute__((ext_vector_type(4)))  unsigned short u16x4;

#define XCS 262144        // 64^3 x channel stride (f32)
#define OS  250047        // 63^3 out channel stride (f32)
#define SLAB_E 9216       // u16 per kd slab: [2 kh8][9 h][64 w][8 c]
#define KH8_E  4608       // 9*64*8
#define IMG_DW 520        // dwords per epilogue run slot (504 + shift pad)

__device__ __forceinline__ unsigned short f2bf(float f) {
    unsigned int u = __builtin_bit_cast(unsigned int, f);
    return (unsigned short)((u + 0x7fffu + ((u >> 16) & 1u)) >> 16);
}

__global__ __launch_bounds__(256, 4) void conv3d_k2_nt(
    const float* __restrict__ x,
    const float* __restrict__ wgt,
    float* __restrict__ out)
{
    __shared__ __align__(16) unsigned char lds_raw[40960];
    unsigned short* tile  = (unsigned short*)lds_raw;            // [2][2][9][64][8] u16
    unsigned short* strip = (unsigned short*)(lds_raw + 36864);  // [2][16c][64w] u16
    float* img = (float*)lds_raw;                                 // [16][520] f32

    const int t   = threadIdx.x;
    const int l   = t & 63;
    const int wv  = t >> 6;        // wave 0..3
    const int col = l & 31;        // MFMA col (w) / A row (o)
    const int kh8 = l >> 5;        // k-half -> c8 group

    const int h0 = blockIdx.x * 8; // 8 output h rows
    const int d  = blockIdx.y;     // 0..62
    const int b  = blockIdx.z;

    // ---- A fragments: 64 contiguous floats per lane, compile-time shuffle ----
    short8 aF[8];
    {
        f32x4 wreg[16];
        const float* wp = wgt + col * 128 + kh8 * 64;
#pragma unroll
        for (int q = 0; q < 16; ++q) wreg[q] = *(const f32x4*)(wp + q * 4);
#pragma unroll
        for (int tap = 0; tap < 8; ++tap) {
            short8 a;
#pragma unroll
            for (int j = 0; j < 8; ++j) {
                const int k = j * 8 + tap;
                a[j] = (short)f2bf(wreg[k >> 2][k & 3]);
            }
            aF[tap] = a;
        }
    }

    // ---- staging: dwordx4 loads + wave-private 2-stage LDS transpose ----
    // stage A: thread (cA = t>>4, wq = t&15) loads 16-B w-runs of c-plane cA
    //          and parks row h in strip[h&1][cA][*] (double-buffered -> the
    //          unrolled rounds pipeline without aliasing stalls).
    // stage B: thread (wB = l, c-quad = wv) gathers 4 c at w = wB and writes
    //          tile[p][wv>>1][h][wB][ (wv&1)*4 ] (u16x4). Wave-private rows.
    const int cA   = t >> 4;
    const int wq   = t & 15;
    const int wB   = l;
    const int kh8s = wv >> 1;
    const int half = wv & 1;

#pragma unroll
    for (int p = 0; p < 2; ++p) {
        const float* xs = x + (size_t)b * 16 * XCS + (size_t)(d + p) * 4096;
        f32x4 v[9];
#pragma unroll
        for (int h = 0; h < 9; ++h) {
            int hp = h0 + h; if (hp > 63) hp = 63;
            v[h] = *(const f32x4*)(xs + (size_t)cA * XCS + hp * 64 + wq * 4);
        }
#pragma unroll
        for (int h = 0; h < 9; ++h) {
            const int sb = (h & 1) * 1024;
            u16x4 pk;
#pragma unroll
            for (int i = 0; i < 4; ++i) pk[i] = f2bf(v[h][i]);
            *(u16x4*)&strip[sb + cA * 64 + wq * 4] = pk;
            u16x4 q;
#pragma unroll
            for (int i = 0; i < 4; ++i)
                q[i] = strip[sb + (wv * 4 + i) * 64 + wB];
            *(u16x4*)&tile[p * SLAB_E + kh8s * KH8_E + h * 512 + wB * 8 + half * 4] = q;
        }
    }
    __syncthreads();

    // ---- compute: 4 acc tiles (2 h-rows x 2 w-halves) kept in regs ----
    f32x16 acc[2][2];
#pragma unroll
    for (int th = 0; th < 2; ++th) {
        const int hl = wv * 2 + th;
#pragma unroll
        for (int wh = 0; wh < 2; ++wh) {
            const int wb = wh * 32;
            f32x16 a = {};
#pragma unroll
            for (int kd = 0; kd < 2; ++kd)
#pragma unroll
            for (int kh = 0; kh < 2; ++kh)
#pragma unroll
            for (int kw = 0; kw < 2; ++kw) {
                const int tap = kd * 4 + kh * 2 + kw;
                short8 bfrag = *(const short8*)&tile[kd * SLAB_E + kh8 * KH8_E
                    + (hl + kh) * 512 + (wb + col + kw) * 8];
                a = __builtin_amdgcn_mfma_f32_32x32x16_bf16(aF[tap], bfrag, a, 0, 0, 0);
            }
            acc[th][wh] = a;
        }
    }
    __syncthreads();   // done reading tile; LDS becomes the store image

    // ---- epilogue: 2 passes x 16 o-runs, shift-aligned NT dwordx4 drain ----
    const int hvalid = (h0 == 56) ? 7 : 8;
    const int runlen = hvalid * 63;
#pragma unroll
    for (int p = 0; p < 2; ++p) {
        // scatter (y+1)^2 into img, shifted by each run's base&3
#pragma unroll
        for (int th = 0; th < 2; ++th) {
            const int hl = wv * 2 + th;
            if (hl < hvalid) {
#pragma unroll
                for (int wh = 0; wh < 2; ++wh) {
                    const int wc = wh * 32 + col;
                    if (wc < 63) {
#pragma unroll
                        for (int r = 0; r < 8; ++r) {
                            const int rr = p * 8 + r;
                            const int og = (rr & 3) + 8 * (rr >> 2) + 4 * kh8;
                            const int ol = og - p * 16;
                            const unsigned sh =
                                (3u * (unsigned)(32 * b + og) + (unsigned)d + 3u * (unsigned)h0) & 3u;
                            float y = acc[th][wh][rr] + 1.0f;
                            img[ol * IMG_DW + (int)sh + hl * 63 + wc] = y * y;
                        }
                    }
                }
            }
        }
        __syncthreads();
        // drain: wave wv owns 4 runs; head(<=3) + 2x NT dwordx4 + tail(<=3)
#pragma unroll
        for (int orun = 0; orun < 4; ++orun) {
            const int ol = wv * 4 + orun;
            const int og = p * 16 + ol;
            const size_t base_dw = ((size_t)b * 32 + og) * (size_t)OS
                                 + (size_t)d * 3969 + (size_t)h0 * 63;
            float* gp = out + base_dw;
            const int sh = (int)(base_dw & 3);
            const int g0 = (4 - sh) & 3;
            const float* ip = img + ol * IMG_DW + sh;
            if (l < g0) __builtin_nontemporal_store(ip[l], gp + l);
            const int nv = (runlen - g0) >> 2;
#pragma unroll
            for (int rnd = 0; rnd < 2; ++rnd) {
                const int k = rnd * 64 + l;
                if (k < nv) {
                    f32x4 qv = *(const f32x4*)(ip + g0 + 4 * k);
                    __builtin_nontemporal_store(qv, (f32x4*)(gp + g0 + 4 * k));
                }
            }
            const int kt = g0 + 4 * nv + l;
            if (kt < runlen) __builtin_nontemporal_store(ip[kt], gp + kt);
        }
        if (p == 0) __syncthreads();   // img reused by pass-1 scatter
    }
}

extern "C" void kernel_launch(void* const* d_in, const int* in_sizes, int n_in,
                              void* d_out, int out_size, void* d_ws, size_t ws_size,
                              hipStream_t stream) {
    const float* x   = (const float*)d_in[0];
    const float* wgt = (const float*)d_in[1];
    float* out = (float*)d_out;

    dim3 grid(8, 63, 8);    // h-tiles, d, b (linear = L2-friendly map)
    dim3 block(256);
    conv3d_k2_nt<<<grid, block, 0, stream>>>(x, wgt, out);
}